// Round 1
// baseline (424.692 us; speedup 1.0000x reference)
//
#include <hip/hip_runtime.h>
#include <cstdint>
#include <cmath>

// Problem constants (fixed by setup_inputs)
#define NROWS 32768
#define HD    1024
#define NMOT  128
#define NCLS  16
#define KSEL  32
#define EPSV  1e-4f

typedef __attribute__((ext_vector_type(4))) float  f32x4;
typedef __attribute__((ext_vector_type(8))) __bf16 bf16x8;
typedef __attribute__((ext_vector_type(4))) __bf16 bf16x4;
typedef unsigned long long u64;

// ---- workspace layout (in float slots) ----
// wsf[0..512)          : lossP[512] — per-GEMM-block loss partials
// wsf[512..640)        : mcnt[128]  — per-motif completion counters (ints)
// wsf[1024..132096)    : s1k[128][512] u64 — stage-1 top-32 keys per (motif,chunk)
// wsf[132096..394240)  : cd[32768][8] — per-row dist to its 8 same-class motifs
#define WS_LP   0
#define WS_MC   512
#define WS_S1K  1024
#define WS_CD   132096
#define CAPC    256     // per-(class,2048-row-chunk) candidate cap: mean 128, sigma 11

static __device__ __forceinline__ float dot4(float4 v) {
    return v.x * v.x + v.y * v.y + v.z * v.z + v.w * v.w;
}

static __device__ __forceinline__ bf16x4 cvt4(float4 v) {
    bf16x4 t;
    t[0] = (__bf16)v.x; t[1] = (__bf16)v.y; t[2] = (__bf16)v.z; t[3] = (__bf16)v.w;
    return t;
}

static __device__ __forceinline__ bf16x8 cvt8(float4 a, float4 b) {
    bf16x8 t;
    t[0] = (__bf16)a.x; t[1] = (__bf16)a.y; t[2] = (__bf16)a.z; t[3] = (__bf16)a.w;
    t[4] = (__bf16)b.x; t[5] = (__bf16)b.y; t[6] = (__bf16)b.z; t[7] = (__bf16)b.w;
    return t;
}

// packed key: ascending u64 order == (value descending, index ascending)
static __device__ __forceinline__ u64 pack_key(float v, int idx) {
    unsigned int b = __float_as_uint(v);
    unsigned int mo = (b & 0x80000000u) ? ~b : (b | 0x80000000u); // ascending map
    unsigned int khi = ~mo;                                      // descending
    return ((u64)khi << 32) | (unsigned int)idx;
}

// ---------------------------------------------------------------------------
// Kernel 1: bf16-MFMA GEMM (z @ M^T) with prep fully folded in.
//  - B-staging loads mv as f32 (L2-resident) and converts to bf16 in-register
//  - motif squared norms accumulate during staging -> LDS (smn)
//  - loss written as per-block partial (no atomic, no zeroing pass)
//  - block 0 zeroes the 128 per-motif completion counters for kernel 2
// Tile: 64 rows x 128 cols, BK=32. A ring: 4 slabs (HBM). B ring: 2 slabs (L2).
// ---------------------------------------------------------------------------
#define BM 64
#define BN 128
#define BK 32
#define NS (HD / BK)   // 32 k-slabs
#define SA 40          // padded LDS stride in bf16 elems (80B)

__global__ __launch_bounds__(256, 2) void gemm_fused(
    const float* __restrict__ z, const float* __restrict__ mv,
    float* __restrict__ cd, const int* __restrict__ y,
    float* __restrict__ lossP, int* __restrict__ mcnt) {
    __shared__ __bf16 As[2][BM * SA];
    __shared__ __bf16 Bs[2][BN * SA];
    __shared__ float  szn[BM];
    __shared__ float  smn[BN];
    __shared__ int    ly[BM];
    __shared__ float  spm[2][BM];
    __shared__ float  sns[2][BM];

    const int tid  = threadIdx.x;
    const int row0 = blockIdx.x * BM;
    const int lane = tid & 63;
    const int wave = tid >> 6;
    const int wr   = wave >> 1;   // 0..1 : 32-row strip
    const int wc   = wave & 1;    // 0..1 : 64-col strip
    const int l15  = lane & 15;
    const int quad = lane >> 4;

    const int sq = tid & 7;       // A staging: float4 slot in 32-wide k slab
    const int sr = tid >> 3;      // A staging: row 0..31 (rows sr, sr+32)
    const int bq = tid & 3;       // B staging: 8-float chunk in k-slab
    const int br = tid >> 2;      // B staging: row 0..63 (rows br, br+64)

    if (blockIdx.x == 0 && tid < NMOT) mcnt[tid] = 0;
    if (tid < BM) ly[tid] = y[row0 + tid];

    f32x4 acc[2][4];
#pragma unroll
    for (int i = 0; i < 2; ++i)
#pragma unroll
        for (int j = 0; j < 4; ++j) acc[i][j] = (f32x4){0.f, 0.f, 0.f, 0.f};

    float zsq0 = 0.f, zsq1 = 0.f;
    float msq0 = 0.f, msq1 = 0.f;

    const float* zb = z  + (size_t)(row0 + sr) * HD + sq * 4;
    const float* bb = mv + (size_t)br * HD + bq * 8;

    // ---- register rings: A 4 slabs (HBM latency), B 2 slabs (L2 latency) ----
    float4 ra0[4], ra1[4];
    float4 rb0[2][2], rb1[2][2];
#pragma unroll
    for (int s = 0; s < 4; ++s) {
        ra0[s] = *(const float4*)(zb + s * BK);
        ra1[s] = *(const float4*)(zb + s * BK + 32 * HD);
    }
#pragma unroll
    for (int s = 0; s < 2; ++s) {
        rb0[s][0] = *(const float4*)(bb + s * BK);
        rb0[s][1] = *(const float4*)(bb + s * BK + 4);
        rb1[s][0] = *(const float4*)(bb + s * BK + 64 * HD);
        rb1[s][1] = *(const float4*)(bb + s * BK + 64 * HD + 4);
    }
    // stage slab 0 into buf0, then refill freed slots (A: slab 4, B: slab 2)
    *(bf16x4*)&As[0][sr * SA + sq * 4]        = cvt4(ra0[0]);
    *(bf16x4*)&As[0][(sr + 32) * SA + sq * 4] = cvt4(ra1[0]);
    *(bf16x8*)&Bs[0][br * SA + bq * 8]        = cvt8(rb0[0][0], rb0[0][1]);
    *(bf16x8*)&Bs[0][(br + 64) * SA + bq * 8] = cvt8(rb1[0][0], rb1[0][1]);
    zsq0 += dot4(ra0[0]); zsq1 += dot4(ra1[0]);
    msq0 += dot4(rb0[0][0]) + dot4(rb0[0][1]);
    msq1 += dot4(rb1[0][0]) + dot4(rb1[0][1]);
    ra0[0] = *(const float4*)(zb + 4 * BK);
    ra1[0] = *(const float4*)(zb + 4 * BK + 32 * HD);
    rb0[0][0] = *(const float4*)(bb + 2 * BK);
    rb0[0][1] = *(const float4*)(bb + 2 * BK + 4);
    rb1[0][0] = *(const float4*)(bb + 2 * BK + 64 * HD);
    rb1[0][1] = *(const float4*)(bb + 2 * BK + 64 * HD + 4);
    __syncthreads();

    // main loop: iter kt consumes LDS slab kt, stages slab kt+1,
    // issues A loads for slab kt+5 and B loads for slab kt+3.
    for (int it = 0; it < NS / 4; ++it) {
#pragma unroll
        for (int u = 0; u < 4; ++u) {
            const int kt = it * 4 + u;
            const int rbuf = kt & 1;
            const int ko = quad * 8;
            // step1: fragment reads for slab kt
            bf16x8 af[2], bfr[4];
#pragma unroll
            for (int i = 0; i < 2; ++i)
                af[i] = *(const bf16x8*)&As[rbuf][(wr * 32 + i * 16 + l15) * SA + ko];
#pragma unroll
            for (int j = 0; j < 4; ++j)
                bfr[j] = *(const bf16x8*)&Bs[rbuf][(wc * 64 + j * 16 + l15) * SA + ko];
            // step2: stage slab kt+1, refill rings
            if (kt + 1 < NS) {
                const int w  = (kt + 1) & 1;
                const int sA = (kt + 1) & 3;
                const int sB = (kt + 1) & 1;
                *(bf16x4*)&As[w][sr * SA + sq * 4]        = cvt4(ra0[sA]);
                *(bf16x4*)&As[w][(sr + 32) * SA + sq * 4] = cvt4(ra1[sA]);
                *(bf16x8*)&Bs[w][br * SA + bq * 8]        = cvt8(rb0[sB][0], rb0[sB][1]);
                *(bf16x8*)&Bs[w][(br + 64) * SA + bq * 8] = cvt8(rb1[sB][0], rb1[sB][1]);
                zsq0 += dot4(ra0[sA]); zsq1 += dot4(ra1[sA]);
                msq0 += dot4(rb0[sB][0]) + dot4(rb0[sB][1]);
                msq1 += dot4(rb1[sB][0]) + dot4(rb1[sB][1]);
                if (kt + 5 < NS) {
                    const float* zn = zb + (kt + 5) * BK;
                    ra0[sA] = *(const float4*)(zn);
                    ra1[sA] = *(const float4*)(zn + 32 * HD);
                }
                if (kt + 3 < NS) {
                    const float* bn = bb + (kt + 3) * BK;
                    rb0[sB][0] = *(const float4*)(bn);
                    rb0[sB][1] = *(const float4*)(bn + 4);
                    rb1[sB][0] = *(const float4*)(bn + 64 * HD);
                    rb1[sB][1] = *(const float4*)(bn + 64 * HD + 4);
                }
            }
            // step3: MFMA on slab kt
#pragma unroll
            for (int i = 0; i < 2; ++i)
#pragma unroll
                for (int j = 0; j < 4; ++j)
                    acc[i][j] = __builtin_amdgcn_mfma_f32_16x16x32_bf16(
                        af[i], bfr[j], acc[i][j], 0, 0, 0);
            // step4: one barrier per slab
            __syncthreads();
        }
    }

    // reduce ||z||^2 across the 8 staging lanes sharing each row
#pragma unroll
    for (int o = 1; o < 8; o <<= 1) {
        zsq0 += __shfl_xor(zsq0, o, 64);
        zsq1 += __shfl_xor(zsq1, o, 64);
    }
    if (sq == 0) { szn[sr] = zsq0; szn[sr + 32] = zsq1; }
    // reduce ||m||^2 across the 4 staging lanes sharing each motif row
#pragma unroll
    for (int o = 1; o < 4; o <<= 1) {
        msq0 += __shfl_xor(msq0, o, 64);
        msq1 += __shfl_xor(msq1, o, 64);
    }
    if (bq == 0) { smn[br] = msq0; smn[br + 64] = msq1; }
    __syncthreads();

    // epilogue: dist = ||z||^2 + ||m||^2 - 2*xp
    // C/D layout: col = lane&15, row = quad*4 + reg  [verified]
    f32x4 znv[2];
    int rcls[2][4];
#pragma unroll
    for (int i = 0; i < 2; ++i) {
        znv[i] = *(const f32x4*)&szn[wr * 32 + i * 16 + quad * 4];
#pragma unroll
        for (int reg = 0; reg < 4; ++reg)
            rcls[i][reg] = ly[wr * 32 + i * 16 + quad * 4 + reg];
    }
    float pm[2][4], ns[2][4];
#pragma unroll
    for (int i = 0; i < 2; ++i)
#pragma unroll
        for (int reg = 0; reg < 4; ++reg) { pm[i][reg] = 0.f; ns[i][reg] = 0.f; }

#pragma unroll
    for (int j = 0; j < 4; ++j) {
        const int c = wc * 64 + j * 16 + l15;
        const float mc = smn[c];
        const int ccls = c >> 3;
#pragma unroll
        for (int i = 0; i < 2; ++i) {
#pragma unroll
            for (int reg = 0; reg < 4; ++reg) {
                const int row = wr * 32 + i * 16 + quad * 4 + reg;
                float d = znv[i][reg] + mc - 2.f * acc[i][j][reg];
                float r = (d + 1.0f) * __builtin_amdgcn_rcpf(d + EPSV);
                float r2 = r * r;
                float s = r2 * r2 * r;   // ratio^5 == exp(log(ratio)/0.2)
                if (ccls == rcls[i][reg]) {
                    pm[i][reg] = fmaxf(pm[i][reg], s);
                    cd[(size_t)(row0 + row) * 8 + (c & 7)] = d;
                } else {
                    ns[i][reg] += s;
                }
            }
        }
    }
    // reduce across the 16 lanes (l15) of each quad group
#pragma unroll
    for (int o = 1; o < 16; o <<= 1) {
#pragma unroll
        for (int i = 0; i < 2; ++i)
#pragma unroll
            for (int reg = 0; reg < 4; ++reg) {
                pm[i][reg] = fmaxf(pm[i][reg], __shfl_xor(pm[i][reg], o, 64));
                ns[i][reg] += __shfl_xor(ns[i][reg], o, 64);
            }
    }
    if (l15 == 0) {
#pragma unroll
        for (int i = 0; i < 2; ++i)
#pragma unroll
            for (int reg = 0; reg < 4; ++reg) {
                const int row = wr * 32 + i * 16 + quad * 4 + reg;
                spm[wc][row] = pm[i][reg];
                sns[wc][row] = ns[i][reg];
            }
    }
    __syncthreads();
    if (tid < BM) {   // wave 0 only (BM=64)
        float p = fmaxf(spm[0][tid], spm[1][tid]);
        float nsum = sns[0][tid] + sns[1][tid];
        float li = logf((nsum + p) / p);   // = -log(pos/(neg+pos))
#pragma unroll
        for (int o = 1; o < 64; o <<= 1) li += __shfl_xor(li, o, 64);
        if (tid == 0) lossP[blockIdx.x] = li;
    }
}

// ---------------------------------------------------------------------------
// Kernel 2: fused selection + merge. One block per (motif, 2048-row chunk) =
// 2048 blocks. Builds the candidate list inline from y (ballot-compact),
// gathers cd, bitonic-256 sorts, writes its top-32 to s1k. Then the standard
// last-block-done pattern: the 16th finisher for a motif merges all 16 lists
// (bitonic-512), gather-means the 32 selected z rows, tau-blends, writes out.
// Block 0 additionally reduces the 512 loss partials -> out[0].
// ---------------------------------------------------------------------------
__global__ __launch_bounds__(256) void selmerge_k(
    const int* __restrict__ y, const float* __restrict__ cd,
    const float* __restrict__ z, const float* __restrict__ mv,
    const float* __restrict__ lossP, u64* __restrict__ s1k,
    int* __restrict__ mcnt, float* __restrict__ out) {
    __shared__ u64 keys[512];
    __shared__ int clist[CAPC];
    __shared__ int sel[KSEL];
    __shared__ int cnt;
    __shared__ int winflag;
    __shared__ float redf[4];

    const int b = blockIdx.x;
    const int j = b >> 4, chunk = b & 15;
    const int cls = j >> 3, m8 = j & 7;
    const int tid = threadIdx.x;
    const int lane = tid & 63;

    // ---- phase A: candidate list for (cls, chunk) via ballot-compact ----
    if (tid == 0) cnt = 0;
    __syncthreads();
    const int base = chunk * 2048;
#pragma unroll
    for (int t = 0; t < 8; ++t) {
        const int i = base + t * 256 + tid;
        const bool pred = (y[i] == cls);
        const u64 m = __ballot(pred);
        int wbase = 0;
        if (lane == 0 && m) wbase = atomicAdd(&cnt, (int)__popcll(m));
        wbase = __shfl(wbase, 0, 64);
        if (pred) {
            const int p = wbase + (int)__popcll(m & ((1ull << lane) - 1ull));
            if (p < CAPC) clist[p] = i;
        }
    }
    __syncthreads();
    const int n = cnt < CAPC ? cnt : CAPC;

    // ---- phase B: gather cd, pack keys, bitonic-256 (desc value, asc idx) ----
    u64 key = ~0ull;
    if (tid < n) {
        const int idx = clist[tid];
        key = pack_key(cd[(size_t)idx * 8 + m8], idx);
    }
    keys[tid] = key;
    __syncthreads();
    for (int k = 2; k <= 256; k <<= 1) {
        for (int jj = k >> 1; jj > 0; jj >>= 1) {
            if (tid < 128) {
                const int i  = ((tid & ~(jj - 1)) << 1) | (tid & (jj - 1));
                const int ix = i | jj;
                const u64 A = keys[i], B = keys[ix];
                const bool up = ((i & k) == 0);
                if ((A > B) == up) { keys[i] = B; keys[ix] = A; }
            }
            __syncthreads();
        }
    }
    if (tid < KSEL) s1k[(size_t)j * 512 + chunk * KSEL + tid] = keys[tid];

    // ---- loss reduction (block 0 only; gemm finished at kernel boundary) ----
    if (b == 0) {
        float s = lossP[tid] + lossP[tid + 256];
#pragma unroll
        for (int o = 1; o < 64; o <<= 1) s += __shfl_xor(s, o, 64);
        if (lane == 0) redf[tid >> 6] = s;
    }

    // ---- phase C: last-block-done handshake ----
    __threadfence();              // release own s1k writes to device scope
    __syncthreads();              // all fences done (also publishes redf)
    if (b == 0 && tid == 0)
        out[0] = (redf[0] + redf[1] + redf[2] + redf[3]) * (1.0f / NROWS);
    if (tid == 0) {
        int old = __hip_atomic_fetch_add(&mcnt[j], 1, __ATOMIC_ACQ_REL,
                                         __HIP_MEMORY_SCOPE_AGENT);
        winflag = (old == 15) ? 1 : 0;
    }
    __syncthreads();
    if (!winflag) return;
    __threadfence();              // acquire: see all 16 chunks' s1k writes

    // ---- phase D: merge 16x32 -> top-32 (bitonic-512), gather-mean, blend ----
    keys[tid]       = s1k[(size_t)j * 512 + tid];
    keys[tid + 256] = s1k[(size_t)j * 512 + 256 + tid];
    __syncthreads();
    for (int k = 2; k <= 512; k <<= 1) {
        for (int jj = k >> 1; jj > 0; jj >>= 1) {
            const int i  = ((tid & ~(jj - 1)) << 1) | (tid & (jj - 1));
            const int ix = i | jj;
            const u64 A = keys[i], B = keys[ix];
            const bool up = ((i & k) == 0);
            if ((A > B) == up) { keys[i] = B; keys[ix] = A; }
            __syncthreads();
        }
    }
    if (tid < KSEL) sel[tid] = (int)(keys[tid] & 0xFFFFFFFFu);
    __syncthreads();

    const int h = tid * 4;        // 4 contiguous cols per thread, 1024 total
    float4 s = {0.f, 0.f, 0.f, 0.f};
#pragma unroll 8
    for (int r = 0; r < KSEL; ++r) {
        const float4 v = *(const float4*)&z[(size_t)sel[r] * HD + h];
        s.x += v.x; s.y += v.y; s.z += v.z; s.w += v.w;
    }
    const float4 m4 = *(const float4*)&mv[(size_t)j * HD + h];
    // out is offset by 1 float (loss slot) -> scalar stores (16B misaligned)
    out[1 + (size_t)j * HD + h + 0] = 0.99f * m4.x + 0.01f * (s.x * (1.0f / KSEL));
    out[1 + (size_t)j * HD + h + 1] = 0.99f * m4.y + 0.01f * (s.y * (1.0f / KSEL));
    out[1 + (size_t)j * HD + h + 2] = 0.99f * m4.z + 0.01f * (s.z * (1.0f / KSEL));
    out[1 + (size_t)j * HD + h + 3] = 0.99f * m4.w + 0.01f * (s.w * (1.0f / KSEL));
}

// ---------------------------------------------------------------------------
extern "C" void kernel_launch(void* const* d_in, const int* in_sizes, int n_in,
                              void* d_out, int out_size, void* d_ws, size_t ws_size,
                              hipStream_t stream) {
    const float* z  = (const float*)d_in[0];
    const float* mv = (const float*)d_in[1];
    const int*   y  = (const int*)d_in[2];
    float* out = (float*)d_out;
    float* wsf = (float*)d_ws;
    float* lossP = wsf + WS_LP;
    int*   mcnt  = (int*)(wsf + WS_MC);
    u64*   s1k   = (u64*)(wsf + WS_S1K);
    float* cd    = wsf + WS_CD;

    hipLaunchKernelGGL(gemm_fused, dim3(NROWS / BM), dim3(256), 0, stream,
                       z, mv, cd, y, lossP, mcnt);
    hipLaunchKernelGGL(selmerge_k, dim3(NMOT * 16), dim3(256), 0, stream,
                       y, cd, z, mv, lossP, s1k, mcnt, out);
}

// Round 2
// 291.768 us; speedup vs baseline: 1.4556x; 1.4556x over previous
//
#include <hip/hip_runtime.h>
#include <cstdint>
#include <cmath>

// Problem constants (fixed by setup_inputs)
#define NROWS 32768
#define HD    1024
#define NMOT  128
#define NCLS  16
#define KSEL  32
#define EPSV  1e-4f

typedef __attribute__((ext_vector_type(4))) float  f32x4;
typedef __attribute__((ext_vector_type(8))) __bf16 bf16x8;
typedef __attribute__((ext_vector_type(4))) __bf16 bf16x4;
typedef unsigned long long u64;

// ---- workspace layout (in float slots) ----
// wsf[0..512)        : lossP[512] — per-GEMM-block loss partials
// wsf[1024..263168)  : cd[32768][8] — per-row dist to its 8 same-class motifs
#define WS_LP   0
#define WS_CD   1024
#define CAPC    256     // per-(class,2048-row-chunk) candidate cap: mean 128, sigma 11

static __device__ __forceinline__ float dot4(float4 v) {
    return v.x * v.x + v.y * v.y + v.z * v.z + v.w * v.w;
}

static __device__ __forceinline__ bf16x4 cvt4(float4 v) {
    bf16x4 t;
    t[0] = (__bf16)v.x; t[1] = (__bf16)v.y; t[2] = (__bf16)v.z; t[3] = (__bf16)v.w;
    return t;
}

static __device__ __forceinline__ bf16x8 cvt8(float4 a, float4 b) {
    bf16x8 t;
    t[0] = (__bf16)a.x; t[1] = (__bf16)a.y; t[2] = (__bf16)a.z; t[3] = (__bf16)a.w;
    t[4] = (__bf16)b.x; t[5] = (__bf16)b.y; t[6] = (__bf16)b.z; t[7] = (__bf16)b.w;
    return t;
}

// packed key: ascending u64 order == (value descending, index ascending)
static __device__ __forceinline__ u64 pack_key(float v, int idx) {
    unsigned int b = __float_as_uint(v);
    unsigned int mo = (b & 0x80000000u) ? ~b : (b | 0x80000000u); // ascending map
    unsigned int khi = ~mo;                                      // descending
    return ((u64)khi << 32) | (unsigned int)idx;
}

// ---------------------------------------------------------------------------
// Kernel 1: bf16-MFMA GEMM (z @ M^T) with prep fully folded in.
//  - B-staging loads mv as f32 (L2-resident) and converts to bf16 in-register
//  - motif squared norms accumulate during staging -> LDS (smn)
//  - loss written as per-block partial (no atomic, no zeroing pass)
// Tile: 64 rows x 128 cols, BK=32. A ring: 4 slabs (HBM). B ring: 2 slabs (L2).
// ---------------------------------------------------------------------------
#define BM 64
#define BN 128
#define BK 32
#define NS (HD / BK)   // 32 k-slabs
#define SA 40          // padded LDS stride in bf16 elems (80B)

__global__ __launch_bounds__(256, 2) void gemm_fused(
    const float* __restrict__ z, const float* __restrict__ mv,
    float* __restrict__ cd, const int* __restrict__ y,
    float* __restrict__ lossP) {
    __shared__ __bf16 As[2][BM * SA];
    __shared__ __bf16 Bs[2][BN * SA];
    __shared__ float  szn[BM];
    __shared__ float  smn[BN];
    __shared__ int    ly[BM];
    __shared__ float  spm[2][BM];
    __shared__ float  sns[2][BM];

    const int tid  = threadIdx.x;
    const int row0 = blockIdx.x * BM;
    const int lane = tid & 63;
    const int wave = tid >> 6;
    const int wr   = wave >> 1;   // 0..1 : 32-row strip
    const int wc   = wave & 1;    // 0..1 : 64-col strip
    const int l15  = lane & 15;
    const int quad = lane >> 4;

    const int sq = tid & 7;       // A staging: float4 slot in 32-wide k slab
    const int sr = tid >> 3;      // A staging: row 0..31 (rows sr, sr+32)
    const int bq = tid & 3;       // B staging: 8-float chunk in k-slab
    const int br = tid >> 2;      // B staging: row 0..63 (rows br, br+64)

    if (tid < BM) ly[tid] = y[row0 + tid];

    f32x4 acc[2][4];
#pragma unroll
    for (int i = 0; i < 2; ++i)
#pragma unroll
        for (int j = 0; j < 4; ++j) acc[i][j] = (f32x4){0.f, 0.f, 0.f, 0.f};

    float zsq0 = 0.f, zsq1 = 0.f;
    float msq0 = 0.f, msq1 = 0.f;

    const float* zb = z  + (size_t)(row0 + sr) * HD + sq * 4;
    const float* bb = mv + (size_t)br * HD + bq * 8;

    // ---- register rings: A 4 slabs (HBM latency), B 2 slabs (L2 latency) ----
    float4 ra0[4], ra1[4];
    float4 rb0[2][2], rb1[2][2];
#pragma unroll
    for (int s = 0; s < 4; ++s) {
        ra0[s] = *(const float4*)(zb + s * BK);
        ra1[s] = *(const float4*)(zb + s * BK + 32 * HD);
    }
#pragma unroll
    for (int s = 0; s < 2; ++s) {
        rb0[s][0] = *(const float4*)(bb + s * BK);
        rb0[s][1] = *(const float4*)(bb + s * BK + 4);
        rb1[s][0] = *(const float4*)(bb + s * BK + 64 * HD);
        rb1[s][1] = *(const float4*)(bb + s * BK + 64 * HD + 4);
    }
    // stage slab 0 into buf0, then refill freed slots (A: slab 4, B: slab 2)
    *(bf16x4*)&As[0][sr * SA + sq * 4]        = cvt4(ra0[0]);
    *(bf16x4*)&As[0][(sr + 32) * SA + sq * 4] = cvt4(ra1[0]);
    *(bf16x8*)&Bs[0][br * SA + bq * 8]        = cvt8(rb0[0][0], rb0[0][1]);
    *(bf16x8*)&Bs[0][(br + 64) * SA + bq * 8] = cvt8(rb1[0][0], rb1[0][1]);
    zsq0 += dot4(ra0[0]); zsq1 += dot4(ra1[0]);
    msq0 += dot4(rb0[0][0]) + dot4(rb0[0][1]);
    msq1 += dot4(rb1[0][0]) + dot4(rb1[0][1]);
    ra0[0] = *(const float4*)(zb + 4 * BK);
    ra1[0] = *(const float4*)(zb + 4 * BK + 32 * HD);
    rb0[0][0] = *(const float4*)(bb + 2 * BK);
    rb0[0][1] = *(const float4*)(bb + 2 * BK + 4);
    rb1[0][0] = *(const float4*)(bb + 2 * BK + 64 * HD);
    rb1[0][1] = *(const float4*)(bb + 2 * BK + 64 * HD + 4);
    __syncthreads();

    // main loop: iter kt consumes LDS slab kt, stages slab kt+1,
    // issues A loads for slab kt+5 and B loads for slab kt+3.
    for (int it = 0; it < NS / 4; ++it) {
#pragma unroll
        for (int u = 0; u < 4; ++u) {
            const int kt = it * 4 + u;
            const int rbuf = kt & 1;
            const int ko = quad * 8;
            // step1: fragment reads for slab kt
            bf16x8 af[2], bfr[4];
#pragma unroll
            for (int i = 0; i < 2; ++i)
                af[i] = *(const bf16x8*)&As[rbuf][(wr * 32 + i * 16 + l15) * SA + ko];
#pragma unroll
            for (int j = 0; j < 4; ++j)
                bfr[j] = *(const bf16x8*)&Bs[rbuf][(wc * 64 + j * 16 + l15) * SA + ko];
            // step2: stage slab kt+1, refill rings
            if (kt + 1 < NS) {
                const int w  = (kt + 1) & 1;
                const int sA = (kt + 1) & 3;
                const int sB = (kt + 1) & 1;
                *(bf16x4*)&As[w][sr * SA + sq * 4]        = cvt4(ra0[sA]);
                *(bf16x4*)&As[w][(sr + 32) * SA + sq * 4] = cvt4(ra1[sA]);
                *(bf16x8*)&Bs[w][br * SA + bq * 8]        = cvt8(rb0[sB][0], rb0[sB][1]);
                *(bf16x8*)&Bs[w][(br + 64) * SA + bq * 8] = cvt8(rb1[sB][0], rb1[sB][1]);
                zsq0 += dot4(ra0[sA]); zsq1 += dot4(ra1[sA]);
                msq0 += dot4(rb0[sB][0]) + dot4(rb0[sB][1]);
                msq1 += dot4(rb1[sB][0]) + dot4(rb1[sB][1]);
                if (kt + 5 < NS) {
                    const float* zn = zb + (kt + 5) * BK;
                    ra0[sA] = *(const float4*)(zn);
                    ra1[sA] = *(const float4*)(zn + 32 * HD);
                }
                if (kt + 3 < NS) {
                    const float* bn = bb + (kt + 3) * BK;
                    rb0[sB][0] = *(const float4*)(bn);
                    rb0[sB][1] = *(const float4*)(bn + 4);
                    rb1[sB][0] = *(const float4*)(bn + 64 * HD);
                    rb1[sB][1] = *(const float4*)(bn + 64 * HD + 4);
                }
            }
            // step3: MFMA on slab kt
#pragma unroll
            for (int i = 0; i < 2; ++i)
#pragma unroll
                for (int j = 0; j < 4; ++j)
                    acc[i][j] = __builtin_amdgcn_mfma_f32_16x16x32_bf16(
                        af[i], bfr[j], acc[i][j], 0, 0, 0);
            // step4: one barrier per slab
            __syncthreads();
        }
    }

    // reduce ||z||^2 across the 8 staging lanes sharing each row
#pragma unroll
    for (int o = 1; o < 8; o <<= 1) {
        zsq0 += __shfl_xor(zsq0, o, 64);
        zsq1 += __shfl_xor(zsq1, o, 64);
    }
    if (sq == 0) { szn[sr] = zsq0; szn[sr + 32] = zsq1; }
    // reduce ||m||^2 across the 4 staging lanes sharing each motif row
#pragma unroll
    for (int o = 1; o < 4; o <<= 1) {
        msq0 += __shfl_xor(msq0, o, 64);
        msq1 += __shfl_xor(msq1, o, 64);
    }
    if (bq == 0) { smn[br] = msq0; smn[br + 64] = msq1; }
    __syncthreads();

    // epilogue: dist = ||z||^2 + ||m||^2 - 2*xp
    // C/D layout: col = lane&15, row = quad*4 + reg  [verified]
    f32x4 znv[2];
    int rcls[2][4];
#pragma unroll
    for (int i = 0; i < 2; ++i) {
        znv[i] = *(const f32x4*)&szn[wr * 32 + i * 16 + quad * 4];
#pragma unroll
        for (int reg = 0; reg < 4; ++reg)
            rcls[i][reg] = ly[wr * 32 + i * 16 + quad * 4 + reg];
    }
    float pm[2][4], ns[2][4];
#pragma unroll
    for (int i = 0; i < 2; ++i)
#pragma unroll
        for (int reg = 0; reg < 4; ++reg) { pm[i][reg] = 0.f; ns[i][reg] = 0.f; }

#pragma unroll
    for (int j = 0; j < 4; ++j) {
        const int c = wc * 64 + j * 16 + l15;
        const float mc = smn[c];
        const int ccls = c >> 3;
#pragma unroll
        for (int i = 0; i < 2; ++i) {
#pragma unroll
            for (int reg = 0; reg < 4; ++reg) {
                const int row = wr * 32 + i * 16 + quad * 4 + reg;
                float d = znv[i][reg] + mc - 2.f * acc[i][j][reg];
                float r = (d + 1.0f) * __builtin_amdgcn_rcpf(d + EPSV);
                float r2 = r * r;
                float s = r2 * r2 * r;   // ratio^5 == exp(log(ratio)/0.2)
                if (ccls == rcls[i][reg]) {
                    pm[i][reg] = fmaxf(pm[i][reg], s);
                    cd[(size_t)(row0 + row) * 8 + (c & 7)] = d;
                } else {
                    ns[i][reg] += s;
                }
            }
        }
    }
    // reduce across the 16 lanes (l15) of each quad group
#pragma unroll
    for (int o = 1; o < 16; o <<= 1) {
#pragma unroll
        for (int i = 0; i < 2; ++i)
#pragma unroll
            for (int reg = 0; reg < 4; ++reg) {
                pm[i][reg] = fmaxf(pm[i][reg], __shfl_xor(pm[i][reg], o, 64));
                ns[i][reg] += __shfl_xor(ns[i][reg], o, 64);
            }
    }
    if (l15 == 0) {
#pragma unroll
        for (int i = 0; i < 2; ++i)
#pragma unroll
            for (int reg = 0; reg < 4; ++reg) {
                const int row = wr * 32 + i * 16 + quad * 4 + reg;
                spm[wc][row] = pm[i][reg];
                sns[wc][row] = ns[i][reg];
            }
    }
    __syncthreads();
    if (tid < BM) {   // wave 0 only (BM=64)
        float p = fmaxf(spm[0][tid], spm[1][tid]);
        float nsum = sns[0][tid] + sns[1][tid];
        float li = logf((nsum + p) / p);   // = -log(pos/(neg+pos))
#pragma unroll
        for (int o = 1; o < 64; o <<= 1) li += __shfl_xor(li, o, 64);
        if (tid == 0) lossP[blockIdx.x] = li;
    }
}

// ---------------------------------------------------------------------------
// Kernel 2: motif-parallel selection + merge. One block per motif (128
// blocks, 4 waves). The 16 row-chunks are processed in 4 groups of 4: each
// wave owns one chunk (ballot-scan of y -> candidate list, cd gather,
// bitonic-256 in its own LDS segment; waves share block barriers in
// lockstep). Then bitonic-512 merges the 16x32 survivors in LDS, gathers the
// 32 selected z rows, tau-blends, writes out. No cross-block communication,
// no device-scope fences. Block 0 also reduces the 512 loss partials.
// ---------------------------------------------------------------------------
__global__ __launch_bounds__(256) void motif_k(
    const int* __restrict__ y, const float* __restrict__ cd,
    const float* __restrict__ z, const float* __restrict__ mv,
    const float* __restrict__ lossP, float* __restrict__ out) {
    __shared__ u64 keys[4][256];
    __shared__ u64 topbuf[512];
    __shared__ int clist[4][CAPC];
    __shared__ int sel[KSEL];
    __shared__ float redf[4];

    const int j = blockIdx.x;
    const int cls = j >> 3, m8 = j & 7;
    const int tid = threadIdx.x;
    const int lane = tid & 63;
    const int wave = tid >> 6;

    // ---- loss reduction (block 0 only; block-uniform branch, barriers ok) --
    if (j == 0) {
        float s = lossP[tid] + lossP[tid + 256];
#pragma unroll
        for (int o = 1; o < 64; o <<= 1) s += __shfl_xor(s, o, 64);
        if (lane == 0) redf[wave] = s;
        __syncthreads();
        if (tid == 0)
            out[0] = (redf[0] + redf[1] + redf[2] + redf[3]) * (1.0f / NROWS);
    }

    // ---- per-chunk top-32, 4 chunks at a time (one per wave) ----
    for (int g = 0; g < 4; ++g) {
        const int chunk = g * 4 + wave;
        const int base = chunk * 2048;
        // ballot-compact candidate scan (cnt is wave-uniform)
        int cnt = 0;
#pragma unroll
        for (int t = 0; t < 32; ++t) {
            const int i = base + t * 64 + lane;
            const bool pred = (y[i] == cls);
            const u64 m = __ballot(pred);
            if (pred) {
                const int p = cnt + (int)__popcll(m & ((1ull << lane) - 1ull));
                if (p < CAPC) clist[wave][p] = i;
            }
            cnt += (int)__popcll(m);
        }
        const int n = cnt < CAPC ? cnt : CAPC;
        __syncthreads();
        // gather cd, pack keys (4 per lane)
#pragma unroll
        for (int t = 0; t < 4; ++t) {
            const int l = t * 64 + lane;
            u64 key = ~0ull;
            if (l < n) {
                const int idx = clist[wave][l];
                key = pack_key(cd[(size_t)idx * 8 + m8], idx);
            }
            keys[wave][l] = key;
        }
        __syncthreads();
        // bitonic-256 per wave segment (2 pairs per lane), shared barriers
        for (int k = 2; k <= 256; k <<= 1) {
            for (int jj = k >> 1; jj > 0; jj >>= 1) {
#pragma unroll
                for (int t = 0; t < 2; ++t) {
                    const int pid = t * 64 + lane;
                    const int i  = ((pid & ~(jj - 1)) << 1) | (pid & (jj - 1));
                    const int ix = i | jj;
                    const u64 A = keys[wave][i], B = keys[wave][ix];
                    const bool up = ((i & k) == 0);
                    if ((A > B) == up) { keys[wave][i] = B; keys[wave][ix] = A; }
                }
                __syncthreads();
            }
        }
        // emit this chunk's top-32
        if (lane < KSEL) topbuf[chunk * KSEL + lane] = keys[wave][lane];
        __syncthreads();
    }

    // ---- merge: bitonic-512 over the 16x32 survivors ----
    for (int k = 2; k <= 512; k <<= 1) {
        for (int jj = k >> 1; jj > 0; jj >>= 1) {
            const int i  = ((tid & ~(jj - 1)) << 1) | (tid & (jj - 1));
            const int ix = i | jj;
            const u64 A = topbuf[i], B = topbuf[ix];
            const bool up = ((i & k) == 0);
            if ((A > B) == up) { topbuf[i] = B; topbuf[ix] = A; }
            __syncthreads();
        }
    }
    if (tid < KSEL) sel[tid] = (int)(topbuf[tid] & 0xFFFFFFFFu);
    __syncthreads();

    // ---- gather-mean of 32 selected z rows, tau-blend, write ----
    const int h = tid * 4;        // 4 contiguous cols per thread, 1024 total
    float4 s = {0.f, 0.f, 0.f, 0.f};
#pragma unroll 8
    for (int r = 0; r < KSEL; ++r) {
        const float4 v = *(const float4*)&z[(size_t)sel[r] * HD + h];
        s.x += v.x; s.y += v.y; s.z += v.z; s.w += v.w;
    }
    const float4 m4 = *(const float4*)&mv[(size_t)j * HD + h];
    // out is offset by 1 float (loss slot) -> scalar stores (16B misaligned)
    out[1 + (size_t)j * HD + h + 0] = 0.99f * m4.x + 0.01f * (s.x * (1.0f / KSEL));
    out[1 + (size_t)j * HD + h + 1] = 0.99f * m4.y + 0.01f * (s.y * (1.0f / KSEL));
    out[1 + (size_t)j * HD + h + 2] = 0.99f * m4.z + 0.01f * (s.z * (1.0f / KSEL));
    out[1 + (size_t)j * HD + h + 3] = 0.99f * m4.w + 0.01f * (s.w * (1.0f / KSEL));
}

// ---------------------------------------------------------------------------
extern "C" void kernel_launch(void* const* d_in, const int* in_sizes, int n_in,
                              void* d_out, int out_size, void* d_ws, size_t ws_size,
                              hipStream_t stream) {
    const float* z  = (const float*)d_in[0];
    const float* mv = (const float*)d_in[1];
    const int*   y  = (const int*)d_in[2];
    float* out = (float*)d_out;
    float* wsf = (float*)d_ws;
    float* lossP = wsf + WS_LP;
    float* cd    = wsf + WS_CD;

    hipLaunchKernelGGL(gemm_fused, dim3(NROWS / BM), dim3(256), 0, stream,
                       z, mv, cd, y, lossP);
    hipLaunchKernelGGL(motif_k,    dim3(NMOT), dim3(256), 0, stream,
                       y, cd, z, mv, lossP, out);
}

// Round 3
// 229.705 us; speedup vs baseline: 1.8489x; 1.2702x over previous
//
#include <hip/hip_runtime.h>
#include <cstdint>
#include <cmath>

// Problem constants (fixed by setup_inputs)
#define NROWS 32768
#define HD    1024
#define NMOT  128
#define NCLS  16
#define KSEL  32
#define EPSV  1e-4f

typedef __attribute__((ext_vector_type(4))) float  f32x4;
typedef __attribute__((ext_vector_type(8))) __bf16 bf16x8;
typedef __attribute__((ext_vector_type(4))) __bf16 bf16x4;
typedef unsigned long long u64;

// ---- workspace layout (in float slots) ----
// wsf[0..512)         : lossP[512] — per-GEMM-block loss partials
// wsf[1024..132096)   : s1k[128][512] u64 — stage-1 top-32 keys per (motif,chunk)
// wsf[132096..394240) : cd[32768][8] — per-row dist to its 8 same-class motifs
#define WS_LP   0
#define WS_S1K  1024
#define WS_CD   132096
#define CAPC    256     // per-(class,2048-row-chunk) candidate cap: mean 128, sigma 11

static __device__ __forceinline__ float dot4(float4 v) {
    return v.x * v.x + v.y * v.y + v.z * v.z + v.w * v.w;
}

static __device__ __forceinline__ bf16x4 cvt4(float4 v) {
    bf16x4 t;
    t[0] = (__bf16)v.x; t[1] = (__bf16)v.y; t[2] = (__bf16)v.z; t[3] = (__bf16)v.w;
    return t;
}

static __device__ __forceinline__ bf16x8 cvt8(float4 a, float4 b) {
    bf16x8 t;
    t[0] = (__bf16)a.x; t[1] = (__bf16)a.y; t[2] = (__bf16)a.z; t[3] = (__bf16)a.w;
    t[4] = (__bf16)b.x; t[5] = (__bf16)b.y; t[6] = (__bf16)b.z; t[7] = (__bf16)b.w;
    return t;
}

// packed key: ascending u64 order == (value descending, index ascending)
static __device__ __forceinline__ u64 pack_key(float v, int idx) {
    unsigned int b = __float_as_uint(v);
    unsigned int mo = (b & 0x80000000u) ? ~b : (b | 0x80000000u); // ascending map
    unsigned int khi = ~mo;                                      // descending
    return ((u64)khi << 32) | (unsigned int)idx;
}

// ---------------------------------------------------------------------------
// Kernel 1: bf16-MFMA GEMM (z @ M^T) with prep fully folded in.
//  - B-staging loads mv as f32 (L2-resident) and converts to bf16 in-register
//  - motif squared norms accumulate during staging -> LDS (smn)
//  - loss written as per-block partial (no atomic, no zeroing pass)
// Tile: 64 rows x 128 cols, BK=32. A ring: 4 slabs (HBM). B ring: 2 slabs (L2).
// ---------------------------------------------------------------------------
#define BM 64
#define BN 128
#define BK 32
#define NS (HD / BK)   // 32 k-slabs
#define SA 40          // padded LDS stride in bf16 elems (80B)

__global__ __launch_bounds__(256, 2) void gemm_fused(
    const float* __restrict__ z, const float* __restrict__ mv,
    float* __restrict__ cd, const int* __restrict__ y,
    float* __restrict__ lossP) {
    __shared__ __bf16 As[2][BM * SA];
    __shared__ __bf16 Bs[2][BN * SA];
    __shared__ float  szn[BM];
    __shared__ float  smn[BN];
    __shared__ int    ly[BM];
    __shared__ float  spm[2][BM];
    __shared__ float  sns[2][BM];

    const int tid  = threadIdx.x;
    const int row0 = blockIdx.x * BM;
    const int lane = tid & 63;
    const int wave = tid >> 6;
    const int wr   = wave >> 1;   // 0..1 : 32-row strip
    const int wc   = wave & 1;    // 0..1 : 64-col strip
    const int l15  = lane & 15;
    const int quad = lane >> 4;

    const int sq = tid & 7;       // A staging: float4 slot in 32-wide k slab
    const int sr = tid >> 3;      // A staging: row 0..31 (rows sr, sr+32)
    const int bq = tid & 3;       // B staging: 8-float chunk in k-slab
    const int br = tid >> 2;      // B staging: row 0..63 (rows br, br+64)

    if (tid < BM) ly[tid] = y[row0 + tid];

    f32x4 acc[2][4];
#pragma unroll
    for (int i = 0; i < 2; ++i)
#pragma unroll
        for (int j = 0; j < 4; ++j) acc[i][j] = (f32x4){0.f, 0.f, 0.f, 0.f};

    float zsq0 = 0.f, zsq1 = 0.f;
    float msq0 = 0.f, msq1 = 0.f;

    const float* zb = z  + (size_t)(row0 + sr) * HD + sq * 4;
    const float* bb = mv + (size_t)br * HD + bq * 8;

    // ---- register rings: A 4 slabs (HBM latency), B 2 slabs (L2 latency) ----
    float4 ra0[4], ra1[4];
    float4 rb0[2][2], rb1[2][2];
#pragma unroll
    for (int s = 0; s < 4; ++s) {
        ra0[s] = *(const float4*)(zb + s * BK);
        ra1[s] = *(const float4*)(zb + s * BK + 32 * HD);
    }
#pragma unroll
    for (int s = 0; s < 2; ++s) {
        rb0[s][0] = *(const float4*)(bb + s * BK);
        rb0[s][1] = *(const float4*)(bb + s * BK + 4);
        rb1[s][0] = *(const float4*)(bb + s * BK + 64 * HD);
        rb1[s][1] = *(const float4*)(bb + s * BK + 64 * HD + 4);
    }
    // stage slab 0 into buf0, then refill freed slots (A: slab 4, B: slab 2)
    *(bf16x4*)&As[0][sr * SA + sq * 4]        = cvt4(ra0[0]);
    *(bf16x4*)&As[0][(sr + 32) * SA + sq * 4] = cvt4(ra1[0]);
    *(bf16x8*)&Bs[0][br * SA + bq * 8]        = cvt8(rb0[0][0], rb0[0][1]);
    *(bf16x8*)&Bs[0][(br + 64) * SA + bq * 8] = cvt8(rb1[0][0], rb1[0][1]);
    zsq0 += dot4(ra0[0]); zsq1 += dot4(ra1[0]);
    msq0 += dot4(rb0[0][0]) + dot4(rb0[0][1]);
    msq1 += dot4(rb1[0][0]) + dot4(rb1[0][1]);
    ra0[0] = *(const float4*)(zb + 4 * BK);
    ra1[0] = *(const float4*)(zb + 4 * BK + 32 * HD);
    rb0[0][0] = *(const float4*)(bb + 2 * BK);
    rb0[0][1] = *(const float4*)(bb + 2 * BK + 4);
    rb1[0][0] = *(const float4*)(bb + 2 * BK + 64 * HD);
    rb1[0][1] = *(const float4*)(bb + 2 * BK + 64 * HD + 4);
    __syncthreads();

    // main loop: iter kt consumes LDS slab kt, stages slab kt+1,
    // issues A loads for slab kt+5 and B loads for slab kt+3.
    for (int it = 0; it < NS / 4; ++it) {
#pragma unroll
        for (int u = 0; u < 4; ++u) {
            const int kt = it * 4 + u;
            const int rbuf = kt & 1;
            const int ko = quad * 8;
            // step1: fragment reads for slab kt
            bf16x8 af[2], bfr[4];
#pragma unroll
            for (int i = 0; i < 2; ++i)
                af[i] = *(const bf16x8*)&As[rbuf][(wr * 32 + i * 16 + l15) * SA + ko];
#pragma unroll
            for (int j = 0; j < 4; ++j)
                bfr[j] = *(const bf16x8*)&Bs[rbuf][(wc * 64 + j * 16 + l15) * SA + ko];
            // step2: stage slab kt+1, refill rings
            if (kt + 1 < NS) {
                const int w  = (kt + 1) & 1;
                const int sA = (kt + 1) & 3;
                const int sB = (kt + 1) & 1;
                *(bf16x4*)&As[w][sr * SA + sq * 4]        = cvt4(ra0[sA]);
                *(bf16x4*)&As[w][(sr + 32) * SA + sq * 4] = cvt4(ra1[sA]);
                *(bf16x8*)&Bs[w][br * SA + bq * 8]        = cvt8(rb0[sB][0], rb0[sB][1]);
                *(bf16x8*)&Bs[w][(br + 64) * SA + bq * 8] = cvt8(rb1[sB][0], rb1[sB][1]);
                zsq0 += dot4(ra0[sA]); zsq1 += dot4(ra1[sA]);
                msq0 += dot4(rb0[sB][0]) + dot4(rb0[sB][1]);
                msq1 += dot4(rb1[sB][0]) + dot4(rb1[sB][1]);
                if (kt + 5 < NS) {
                    const float* zn = zb + (kt + 5) * BK;
                    ra0[sA] = *(const float4*)(zn);
                    ra1[sA] = *(const float4*)(zn + 32 * HD);
                }
                if (kt + 3 < NS) {
                    const float* bn = bb + (kt + 3) * BK;
                    rb0[sB][0] = *(const float4*)(bn);
                    rb0[sB][1] = *(const float4*)(bn + 4);
                    rb1[sB][0] = *(const float4*)(bn + 64 * HD);
                    rb1[sB][1] = *(const float4*)(bn + 64 * HD + 4);
                }
            }
            // step3: MFMA on slab kt
#pragma unroll
            for (int i = 0; i < 2; ++i)
#pragma unroll
                for (int j = 0; j < 4; ++j)
                    acc[i][j] = __builtin_amdgcn_mfma_f32_16x16x32_bf16(
                        af[i], bfr[j], acc[i][j], 0, 0, 0);
            // step4: one barrier per slab
            __syncthreads();
        }
    }

    // reduce ||z||^2 across the 8 staging lanes sharing each row
#pragma unroll
    for (int o = 1; o < 8; o <<= 1) {
        zsq0 += __shfl_xor(zsq0, o, 64);
        zsq1 += __shfl_xor(zsq1, o, 64);
    }
    if (sq == 0) { szn[sr] = zsq0; szn[sr + 32] = zsq1; }
    // reduce ||m||^2 across the 4 staging lanes sharing each motif row
#pragma unroll
    for (int o = 1; o < 4; o <<= 1) {
        msq0 += __shfl_xor(msq0, o, 64);
        msq1 += __shfl_xor(msq1, o, 64);
    }
    if (bq == 0) { smn[br] = msq0; smn[br + 64] = msq1; }
    __syncthreads();

    // epilogue: dist = ||z||^2 + ||m||^2 - 2*xp
    // C/D layout: col = lane&15, row = quad*4 + reg  [verified]
    f32x4 znv[2];
    int rcls[2][4];
#pragma unroll
    for (int i = 0; i < 2; ++i) {
        znv[i] = *(const f32x4*)&szn[wr * 32 + i * 16 + quad * 4];
#pragma unroll
        for (int reg = 0; reg < 4; ++reg)
            rcls[i][reg] = ly[wr * 32 + i * 16 + quad * 4 + reg];
    }
    float pm[2][4], ns[2][4];
#pragma unroll
    for (int i = 0; i < 2; ++i)
#pragma unroll
        for (int reg = 0; reg < 4; ++reg) { pm[i][reg] = 0.f; ns[i][reg] = 0.f; }

#pragma unroll
    for (int j = 0; j < 4; ++j) {
        const int c = wc * 64 + j * 16 + l15;
        const float mc = smn[c];
        const int ccls = c >> 3;
#pragma unroll
        for (int i = 0; i < 2; ++i) {
#pragma unroll
            for (int reg = 0; reg < 4; ++reg) {
                const int row = wr * 32 + i * 16 + quad * 4 + reg;
                float d = znv[i][reg] + mc - 2.f * acc[i][j][reg];
                float r = (d + 1.0f) * __builtin_amdgcn_rcpf(d + EPSV);
                float r2 = r * r;
                float s = r2 * r2 * r;   // ratio^5 == exp(log(ratio)/0.2)
                if (ccls == rcls[i][reg]) {
                    pm[i][reg] = fmaxf(pm[i][reg], s);
                    cd[(size_t)(row0 + row) * 8 + (c & 7)] = d;
                } else {
                    ns[i][reg] += s;
                }
            }
        }
    }
    // reduce across the 16 lanes (l15) of each quad group
#pragma unroll
    for (int o = 1; o < 16; o <<= 1) {
#pragma unroll
        for (int i = 0; i < 2; ++i)
#pragma unroll
            for (int reg = 0; reg < 4; ++reg) {
                pm[i][reg] = fmaxf(pm[i][reg], __shfl_xor(pm[i][reg], o, 64));
                ns[i][reg] += __shfl_xor(ns[i][reg], o, 64);
            }
    }
    if (l15 == 0) {
#pragma unroll
        for (int i = 0; i < 2; ++i)
#pragma unroll
            for (int reg = 0; reg < 4; ++reg) {
                const int row = wr * 32 + i * 16 + quad * 4 + reg;
                spm[wc][row] = pm[i][reg];
                sns[wc][row] = ns[i][reg];
            }
    }
    __syncthreads();
    if (tid < BM) {   // wave 0 only (BM=64)
        float p = fmaxf(spm[0][tid], spm[1][tid]);
        float nsum = sns[0][tid] + sns[1][tid];
        float li = logf((nsum + p) / p);   // = -log(pos/(neg+pos))
#pragma unroll
        for (int o = 1; o < 64; o <<= 1) li += __shfl_xor(li, o, 64);
        if (tid == 0) lossP[blockIdx.x] = li;
    }
}

// ---------------------------------------------------------------------------
// Kernel 2: stage-1 top-32. One block per (motif, 2048-row chunk) = 2048
// blocks (8/CU — good occupancy). Inline ballot-scan of y builds the
// candidate list (<=256), gathers cd, packs keys, bitonic-256 sorts
// (== value desc, idx asc), emits top-32 to s1k. No cross-block comms.
// ---------------------------------------------------------------------------
__global__ __launch_bounds__(256) void sel1_k(const int* __restrict__ y,
                                              const float* __restrict__ cd,
                                              u64* __restrict__ s1k) {
    __shared__ u64 keys[256];
    __shared__ int clist[CAPC];
    __shared__ int cnt;

    const int bid = blockIdx.x;
    const int j = bid >> 4, chunk = bid & 15;
    const int cls = j >> 3, m8 = j & 7;
    const int tid = threadIdx.x;
    const int lane = tid & 63;

    // ---- ballot-compact candidate scan over this chunk's 2048 rows ----
    if (tid == 0) cnt = 0;
    __syncthreads();
    const int base = chunk * 2048;
#pragma unroll
    for (int t = 0; t < 8; ++t) {
        const int i = base + t * 256 + tid;
        const bool pred = (y[i] == cls);
        const u64 m = __ballot(pred);
        int wbase = 0;
        if (lane == 0 && m) wbase = atomicAdd(&cnt, (int)__popcll(m));
        wbase = __shfl(wbase, 0, 64);
        if (pred) {
            const int p = wbase + (int)__popcll(m & ((1ull << lane) - 1ull));
            if (p < CAPC) clist[p] = i;
        }
    }
    __syncthreads();
    const int n = cnt < CAPC ? cnt : CAPC;

    // ---- gather cd, pack keys ----
    u64 key = ~0ull;
    if (tid < n) {
        const int idx = clist[tid];
        key = pack_key(cd[(size_t)idx * 8 + m8], idx);
    }
    keys[tid] = key;
    __syncthreads();

    // bitonic sort, 256 elems, threads 0..127 act (1 pair each), ascending
    for (int k = 2; k <= 256; k <<= 1) {
        for (int jj = k >> 1; jj > 0; jj >>= 1) {
            if (tid < 128) {
                const int i  = ((tid & ~(jj - 1)) << 1) | (tid & (jj - 1));
                const int ix = i | jj;
                const u64 A = keys[i], B = keys[ix];
                const bool up = ((i & k) == 0);
                if ((A > B) == up) { keys[i] = B; keys[ix] = A; }
            }
            __syncthreads();
        }
    }
    if (tid < KSEL) s1k[(size_t)j * 512 + chunk * KSEL + tid] = keys[tid];
}

// ---------------------------------------------------------------------------
// Kernel 3: merge 16x32 stage-1 keys -> global top-32 (bitonic-512, redundant
// per column-quarter), gather-mean of selected z rows, tau-blend, write.
// 512 blocks: (motif j = b>>2, column quarter q = b&3). Block 0 also reduces
// the 512 loss partials -> out[0].
// ---------------------------------------------------------------------------
__global__ __launch_bounds__(256) void merge_k(
    const float* __restrict__ z, const float* __restrict__ mv,
    const u64* __restrict__ s1k, const float* __restrict__ lossP,
    float* __restrict__ out) {
    __shared__ u64 keys[512];
    __shared__ int sel[KSEL];
    __shared__ float redf[4];

    const int b = blockIdx.x;
    const int j = b >> 2, q = b & 3;
    const int tid = threadIdx.x;
    const int lane = tid & 63;
    const int wave = tid >> 6;

    // ---- loss reduction (block 0 only; block-uniform branch, barriers ok) --
    if (b == 0) {
        float s = lossP[tid] + lossP[tid + 256];
#pragma unroll
        for (int o = 1; o < 64; o <<= 1) s += __shfl_xor(s, o, 64);
        if (lane == 0) redf[wave] = s;
        __syncthreads();
        if (tid == 0)
            out[0] = (redf[0] + redf[1] + redf[2] + redf[3]) * (1.0f / NROWS);
    }

    keys[tid]       = s1k[(size_t)j * 512 + tid];
    keys[tid + 256] = s1k[(size_t)j * 512 + 256 + tid];
    __syncthreads();

    // bitonic sort, 512 elems, 256 threads = 1 pair each, ascending
    for (int k = 2; k <= 512; k <<= 1) {
        for (int jj = k >> 1; jj > 0; jj >>= 1) {
            const int i  = ((tid & ~(jj - 1)) << 1) | (tid & (jj - 1));
            const int ix = i | jj;
            const u64 A = keys[i], B = keys[ix];
            const bool up = ((i & k) == 0);
            if ((A > B) == up) { keys[i] = B; keys[ix] = A; }
            __syncthreads();
        }
    }
    if (tid < KSEL) sel[tid] = (int)(keys[tid] & 0xFFFFFFFFu);
    __syncthreads();

    const int h = q * 256 + tid;
    float s = 0.f;
#pragma unroll 8
    for (int r = 0; r < KSEL; ++r) s += z[(size_t)sel[r] * HD + h];
    out[1 + (size_t)j * HD + h] =
        0.99f * mv[(size_t)j * HD + h] + 0.01f * (s * (1.0f / KSEL));
}

// ---------------------------------------------------------------------------
extern "C" void kernel_launch(void* const* d_in, const int* in_sizes, int n_in,
                              void* d_out, int out_size, void* d_ws, size_t ws_size,
                              hipStream_t stream) {
    const float* z  = (const float*)d_in[0];
    const float* mv = (const float*)d_in[1];
    const int*   y  = (const int*)d_in[2];
    float* out = (float*)d_out;
    float* wsf = (float*)d_ws;
    float* lossP = wsf + WS_LP;
    u64*   s1k   = (u64*)(wsf + WS_S1K);
    float* cd    = wsf + WS_CD;

    hipLaunchKernelGGL(gemm_fused, dim3(NROWS / BM), dim3(256), 0, stream,
                       z, mv, cd, y, lossP);
    hipLaunchKernelGGL(sel1_k,     dim3(NMOT * 16), dim3(256), 0, stream,
                       y, cd, s1k);
    hipLaunchKernelGGL(merge_k,    dim3(NMOT * 4),  dim3(256), 0, stream,
                       z, mv, s1k, lossP, out);
}